// Round 2
// baseline (1205.594 us; speedup 1.0000x reference)
//
#include <hip/hip_runtime.h>
#include <cstdint>
#include <cstddef>

#define NB 32
#define NL 2880
#define NC_TOT 862
#define NPRED 720
#define NSEG 48
#define NMAP 4
#define NK 16
#define NIN 60
#define NOUT 15
#define NCONV 359

// ---------------------------------------------------------------------------
// Kernel 1: per-(b,c) stats + gates in ONE pass over x.  (unchanged)
// block 256 = 32 channels x 8 L-chunks (chunk = 360 l-values = 45 conv outputs)
// grid (ceil(862/32)=27, 32)
// ---------------------------------------------------------------------------
__global__ __launch_bounds__(256) void k1_stats_gates(
    const float* __restrict__ x,
    const float* __restrict__ conv_w,
    const float* __restrict__ conv_b,
    const float* __restrict__ gate_w,
    const float* __restrict__ gate_b,
    float* __restrict__ ws2)
{
  __shared__ __align__(16) float gw[NCONV * 4];   // [d][m]
  __shared__ float red[6][8][32];
  __shared__ float g1s[4];

  const int tid = threadIdx.x;

  for (int idx = tid; idx < NMAP * NCONV; idx += 256) {
    int m = idx / NCONV;
    int d = idx - m * NCONV;
    gw[d * 4 + m] = gate_w[idx];
  }
  __syncthreads();

  if (tid < 64) {
    float p0 = 0.f, p1 = 0.f, p2 = 0.f, p3 = 0.f;
    for (int d = tid; d < NCONV; d += 64) {
      p0 += gw[d * 4 + 0];
      p1 += gw[d * 4 + 1];
      p2 += gw[d * 4 + 2];
      p3 += gw[d * 4 + 3];
    }
    #pragma unroll
    for (int off = 32; off > 0; off >>= 1) {
      p0 += __shfl_down(p0, off, 64);
      p1 += __shfl_down(p1, off, 64);
      p2 += __shfl_down(p2, off, 64);
      p3 += __shfl_down(p3, off, 64);
    }
    if (tid == 0) { g1s[0] = p0; g1s[1] = p1; g1s[2] = p2; g1s[3] = p3; }
  }

  const int cl = tid & 31;
  const int q  = tid >> 5;
  const int c  = blockIdx.x * 32 + cl;
  const int b  = blockIdx.y;
  const bool active = (c < NC_TOT);

  float sum = 0.f, sumsq = 0.f;
  float gacc0 = 0.f, gacc1 = 0.f, gacc2 = 0.f, gacc3 = 0.f;
  float Sw = 0.f;

  if (active) {
    const float* xp = x + (size_t)b * NL * NC_TOT + c;
    float w[NK];
    #pragma unroll
    for (int k = 0; k < NK; ++k) { w[k] = conv_w[c * NK + k]; Sw += w[k]; }

    float A[8], Bv[8];
    const int d0 = q * 45;
    const int d1 = (q == 7) ? NCONV : (d0 + 45);
    const int dlast = q * 45 + 44;

    #pragma unroll
    for (int j = 0; j < 8; ++j) {
      float v = xp[(size_t)(d0 * 8 + j) * NC_TOT];
      A[j] = v; sum += v; sumsq = fmaf(v, v, sumsq);
    }
    for (int d = d0; d < d1; ++d) {
      #pragma unroll
      for (int j = 0; j < 8; ++j)
        Bv[j] = xp[(size_t)(d * 8 + 8 + j) * NC_TOT];
      if (d != dlast) {
        #pragma unroll
        for (int j = 0; j < 8; ++j) { sum += Bv[j]; sumsq = fmaf(Bv[j], Bv[j], sumsq); }
      }
      float cr = 0.f;
      #pragma unroll
      for (int j = 0; j < 8; ++j) cr = fmaf(A[j], w[j], cr);
      #pragma unroll
      for (int j = 0; j < 8; ++j) cr = fmaf(Bv[j], w[j + 8], cr);
      const float4 g4 = *(const float4*)&gw[d * 4];
      gacc0 = fmaf(cr, g4.x, gacc0);
      gacc1 = fmaf(cr, g4.y, gacc1);
      gacc2 = fmaf(cr, g4.z, gacc2);
      gacc3 = fmaf(cr, g4.w, gacc3);
      #pragma unroll
      for (int j = 0; j < 8; ++j) A[j] = Bv[j];
    }
  }

  red[0][q][cl] = sum;
  red[1][q][cl] = sumsq;
  red[2][q][cl] = gacc0;
  red[3][q][cl] = gacc1;
  red[4][q][cl] = gacc2;
  red[5][q][cl] = gacc3;
  __syncthreads();

  if (tid < 32 && active) {
    float t[6];
    #pragma unroll
    for (int cc = 0; cc < 6; ++cc) {
      float s = 0.f;
      #pragma unroll
      for (int qq = 0; qq < 8; ++qq) s += red[cc][qq][tid];
      t[cc] = s;
    }
    const float mean = t[0] * (1.0f / NL);
    const float var  = t[1] * (1.0f / NL) - mean * mean;
    const float sd   = sqrtf(var + 1e-10f);
    const float rstd = 1.0f / sd;
    const float cb   = conv_b[c];
    const float k0   = cb - rstd * mean * Sw;
    float lg[4];
    lg[0] = rstd * t[2] + k0 * g1s[0] + gate_b[0];
    lg[1] = rstd * t[3] + k0 * g1s[1] + gate_b[1];
    lg[2] = rstd * t[4] + k0 * g1s[2] + gate_b[2];
    lg[3] = rstd * t[5] + k0 * g1s[3] + gate_b[3];
    const float mx = fmaxf(fmaxf(lg[0], lg[1]), fmaxf(lg[2], lg[3]));
    const float e0 = expf(lg[0] - mx);
    const float e1 = expf(lg[1] - mx);
    const float e2 = expf(lg[2] - mx);
    const float e3 = expf(lg[3] - mx);
    const float inv = 1.0f / (e0 + e1 + e2 + e3);

    const size_t cs = (size_t)NB * NC_TOT;
    float* o2 = ws2 + (size_t)b * NC_TOT + c;
    o2[0 * cs] = mean;
    o2[1 * cs] = sd;
    o2[2 * cs] = e0 * inv;
    o2[3 * cs] = e1 * inv;
    o2[4 * cs] = e2 * inv;
    o2[5 * cs] = e3 * inv;
  }
}

// ---------------------------------------------------------------------------
// Kernel 2 (rewritten): gated mixture WITHOUT per-channel weff.
//   out[b, o*48+s, c] = sum_m g_m * sum_i x[i*48+s] * W_m[o,i]
//                       - mean * sum_m g_m Wsum_m[o] + sd * sum_m g_m b_m[o] + mean
// block 512 = 32 channels x 16 s-groups (each thread: s = 3*sg + {0,1,2})
// grid (ceil(862/32)=27, 32).  map_w staged once (14.4 KB LDS, wave-uniform
// broadcast reads); x reads / out writes fully 128B-coalesced; no spills.
// ---------------------------------------------------------------------------
#define K2_LOADCH(BUF, I4)                                                   \
  {                                                                          \
    _Pragma("unroll") for (int j = 0; j < 4; ++j) {                          \
      const size_t r = (size_t)(((I4) * 4 + j) * 48 + 3 * sg) * NC_TOT;      \
      BUF[j * 3 + 0] = xp[r];                                                \
      BUF[j * 3 + 1] = xp[r + NC_TOT];                                       \
      BUF[j * 3 + 2] = xp[r + 2 * NC_TOT];                                   \
    }                                                                        \
  }

#define K2_COMPUTE(XV, I4)                                                   \
  {                                                                          \
    _Pragma("unroll") for (int m = 0; m < 4; ++m) {                          \
      const float gm = gv[m];                                                \
      float xg[12];                                                          \
      _Pragma("unroll") for (int t = 0; t < 12; ++t) xg[t] = XV[t] * gm;     \
      _Pragma("unroll") for (int o = 0; o < 15; ++o) {                       \
        const float4 w4 =                                                    \
            *(const float4*)&mw[m * 900 + o * 60 + (I4) * 4];                \
        _Pragma("unroll") for (int k = 0; k < 3; ++k) {                      \
          float a = acc[o][k];                                               \
          a = fmaf(xg[0 * 3 + k], w4.x, a);                                  \
          a = fmaf(xg[1 * 3 + k], w4.y, a);                                  \
          a = fmaf(xg[2 * 3 + k], w4.z, a);                                  \
          a = fmaf(xg[3 * 3 + k], w4.w, a);                                  \
          acc[o][k] = a;                                                     \
        }                                                                    \
      }                                                                      \
    }                                                                        \
  }

__global__ __launch_bounds__(512, 4) void k2_out(
    const float* __restrict__ x,
    const float* __restrict__ map_w,
    const float* __restrict__ map_b,
    const float* __restrict__ ws2,
    float* __restrict__ out)
{
  __shared__ __align__(16) float mw[NMAP * NOUT * NIN];  // 3600 floats, [m][o*60+i]
  __shared__ float mwsum[NMAP][16];                      // sum_i W_m[o,i]
  __shared__ float mb[NMAP][16];

  const int tid = threadIdx.x;
  const int b   = blockIdx.y;
  const int c0  = blockIdx.x * 32;

  const int cl = tid & 31;
  const int sg = tid >> 5;                // 0..15, s = 3*sg+{0,1,2}
  const int c  = c0 + cl;
  const bool active = (c < NC_TOT);
  const int cc = active ? c : (NC_TOT - 1);

  // per-thread stats + gates (coalesced; inactive lanes clamped)
  const size_t cs = (size_t)NB * NC_TOT;
  const float* wsb = ws2 + (size_t)b * NC_TOT + cc;
  const float mean = wsb[0 * cs];
  const float sd   = wsb[1 * cs];
  const float gv[4] = { wsb[2 * cs], wsb[3 * cs], wsb[4 * cs], wsb[5 * cs] };

  const float* xp = x + (size_t)b * NL * NC_TOT + cc;

  // issue chunk-0 x loads before LDS staging (overlap HBM latency)
  float xv0[12], xv1[12];
  K2_LOADCH(xv0, 0);

  // stage map_w (3600 floats) as float4
  for (int idx = tid; idx < 900; idx += 512) {
    ((float4*)mw)[idx] = ((const float4*)map_w)[idx];
  }
  __syncthreads();

  // Wsum[m][o] and map_b staging
  if (tid < 64) {
    const int m = tid >> 4, o = tid & 15;
    if (o < NOUT) {
      float s = 0.f;
      #pragma unroll
      for (int i = 0; i < NIN; ++i) s += mw[m * 900 + o * 60 + i];
      mwsum[m][o] = s;
      mb[m][o] = map_b[m * NOUT + o];
    }
  }
  __syncthreads();

  float acc[NOUT][3];
  #pragma unroll
  for (int o = 0; o < NOUT; ++o)
    #pragma unroll
    for (int k = 0; k < 3; ++k) acc[o][k] = 0.f;

  // main loop: 15 i-chunks, ping-pong prefetch, body kept un-unrolled (I$)
  #pragma unroll 1
  for (int i4 = 0; i4 < 14; i4 += 2) {
    K2_LOADCH(xv1, i4 + 1);
    K2_COMPUTE(xv0, i4);
    K2_LOADCH(xv0, i4 + 2);
    K2_COMPUTE(xv1, i4 + 1);
  }
  K2_COMPUTE(xv0, 14);

  // epilogue: fold -mean*Wsum, +sd*beff, +mean ; coalesced stores
  float* op = out + (size_t)b * NPRED * NC_TOT + cc;
  #pragma unroll
  for (int o = 0; o < NOUT; ++o) {
    float gwo = gv[0] * mwsum[0][o] + gv[1] * mwsum[1][o]
              + gv[2] * mwsum[2][o] + gv[3] * mwsum[3][o];
    float gbo = gv[0] * mb[0][o] + gv[1] * mb[1][o]
              + gv[2] * mb[2][o] + gv[3] * mb[3][o];
    const float cst = fmaf(-mean, gwo, fmaf(sd, gbo, mean));
    if (active) {
      #pragma unroll
      for (int k = 0; k < 3; ++k)
        op[(size_t)(o * 48 + 3 * sg + k) * NC_TOT] = acc[o][k] + cst;
    }
  }
}

// ---------------------------------------------------------------------------
extern "C" void kernel_launch(void* const* d_in, const int* in_sizes, int n_in,
                              void* d_out, int out_size, void* d_ws, size_t ws_size,
                              hipStream_t stream)
{
  (void)in_sizes; (void)n_in; (void)out_size; (void)ws_size;
  const float* x      = (const float*)d_in[0];
  const float* conv_w = (const float*)d_in[1];
  const float* conv_b = (const float*)d_in[2];
  const float* gate_w = (const float*)d_in[3];
  const float* gate_b = (const float*)d_in[4];
  const float* map_w  = (const float*)d_in[5];
  const float* map_b  = (const float*)d_in[6];
  float* out = (float*)d_out;
  float* ws2 = (float*)d_ws;    // 6 * 32 * 862 floats = 662 KB

  dim3 g1((NC_TOT + 31) / 32, NB), b1(256);
  hipLaunchKernelGGL(k1_stats_gates, g1, b1, 0, stream,
                     x, conv_w, conv_b, gate_w, gate_b, ws2);

  dim3 g2((NC_TOT + 31) / 32, NB), b2(512);
  hipLaunchKernelGGL(k2_out, g2, b2, 0, stream,
                     x, map_w, map_b, ws2, out);
}